// Round 2
// baseline (30586.307 us; speedup 1.0000x reference)
//
#include <hip/hip_runtime.h>

#define TT 256
#define BB 256
#define GROUPS 4
#define ROWS_G 64
#define MT 4
#define CWS 32
#define WT_PER_CW 40960
#define WT_TOTAL (WT_PER_CW * CWS)        // 1310720
#define SB_SLOT 32768
#define SB_PER_G (5 * SB_SLOT)            // 163840
#define SB_TOTAL (GROUPS * SB_PER_G)      // 655360
#define HB_PER_G 32768
#define HB_TOTAL (GROUPS * HB_PER_G)      // 131072

typedef __attribute__((ext_vector_type(8))) __bf16 bf16x8;
typedef __attribute__((ext_vector_type(4))) float f32x4;

__device__ __forceinline__ float fsig(float x) { return 1.0f / (1.0f + __expf(-x)); }
__device__ __forceinline__ float ftanh(float x) {
  float e = __expf(-2.0f * fabsf(x));
  float r = (1.0f - e) / (1.0f + e);
  return copysignf(r, x);
}
template <int ACT>
__device__ __forceinline__ float actf(float x) {
  if (ACT == 0) return fsig(x);
  if (ACT == 1) return fmaxf(x, 0.0f);
  if (ACT == 2) return ftanh(x);
  return x;  // identity
}

__device__ __forceinline__ f32x4 mfma16(bf16x8 a, bf16x8 b, f32x4 c) {
  return __builtin_amdgcn_mfma_f32_16x16x32_bf16(a, b, c, 0, 0, 0);
}

// LDS weight tile byte address, XOR-swizzled within rows to break the
// 16-lane same-bank pattern of [n][k] B-fragment reads.
__device__ __forceinline__ int wl_byte(int moff_el, int K, int nl, int k) {
  return moff_el * 2 + nl * K * 2 + ((k * 2) ^ ((nl & 7) << 4));
}

__device__ __forceinline__ bf16x8 bfrag(const __bf16* WL, int moff, int K, int lane, int kb) {
  int kk = kb * 32 + ((lane >> 4) << 3);
  return *(const bf16x8*)((const char*)WL + wl_byte(moff, K, lane & 15, kk));
}

// State buffers: per group slot laid out as [rowblk(16)][cw(32)][4 rows][16 el]
// where el 0..7 = hi bf16 of the WG's 8 state cols, el 8..15 = lo residual.
// Each (rowblk, cw) chunk is 128 B, written exclusively by WG cw -> no
// cross-XCD same-line write sharing.
__device__ __forceinline__ bf16x8 afrag2(const __bf16* p, int m, int lane, int kb, int lo) {
  int row = m * 16 + (lane & 15);
  int k = kb * 32 + ((lane >> 4) << 3);
  int el = ((row >> 2) << 11) + ((k >> 3) << 6) + ((row & 3) << 4) + (lo << 3);
  return *(const bf16x8*)(p + el);
}

__device__ __forceinline__ bf16x8 xfrag(const float* X, int t, int rbase, int m, int lane, int kb) {
  int row = rbase + m * 16 + (lane & 15);
  int k = kb * 32 + ((lane >> 4) << 3);
  const float* p = X + ((size_t)t * BB + row) * 256 + k;
  float4 a = *(const float4*)p;
  float4 b = *(const float4*)(p + 4);
  bf16x8 r;
  r[0] = (__bf16)a.x; r[1] = (__bf16)a.y; r[2] = (__bf16)a.z; r[3] = (__bf16)a.w;
  r[4] = (__bf16)b.x; r[5] = (__bf16)b.y; r[6] = (__bf16)b.z; r[7] = (__bf16)b.w;
  return r;
}

__device__ __forceinline__ void gemm1(const __bf16* A, const __bf16* WL, int mo, int lane,
                                      f32x4 acc[MT]) {
#pragma unroll
  for (int m = 0; m < MT; ++m) acc[m] = (f32x4)(0.0f);
#pragma unroll
  for (int kb = 0; kb < 8; ++kb) {
    bf16x8 B = bfrag(WL, mo, 256, lane, kb);
#pragma unroll
    for (int m = 0; m < MT; ++m) {
      bf16x8 Ah = afrag2(A, m, lane, kb, 0);
      bf16x8 Al = afrag2(A, m, lane, kb, 1);
      acc[m] = mfma16(Ah, B, acc[m]);
      acc[m] = mfma16(Al, B, acc[m]);
    }
  }
}

__device__ __forceinline__ void gemm2(const __bf16* A, const __bf16* WL, int mo1, int mo2,
                                      int lane, f32x4 a1[MT], f32x4 a2[MT]) {
#pragma unroll
  for (int m = 0; m < MT; ++m) { a1[m] = (f32x4)(0.0f); a2[m] = (f32x4)(0.0f); }
#pragma unroll
  for (int kb = 0; kb < 8; ++kb) {
    bf16x8 B1 = bfrag(WL, mo1, 256, lane, kb);
    bf16x8 B2 = bfrag(WL, mo2, 256, lane, kb);
#pragma unroll
    for (int m = 0; m < MT; ++m) {
      bf16x8 Ah = afrag2(A, m, lane, kb, 0);
      bf16x8 Al = afrag2(A, m, lane, kb, 1);
      a1[m] = mfma16(Ah, B1, a1[m]); a1[m] = mfma16(Al, B1, a1[m]);
      a2[m] = mfma16(Ah, B2, a2[m]); a2[m] = mfma16(Al, B2, a2[m]);
    }
  }
}

__device__ __forceinline__ void gemm3(const __bf16* A, const __bf16* WL, int mo1, int mo2,
                                      int mo3, int lane, f32x4 a1[MT], f32x4 a2[MT],
                                      f32x4 a3[MT]) {
#pragma unroll
  for (int m = 0; m < MT; ++m) {
    a1[m] = (f32x4)(0.0f); a2[m] = (f32x4)(0.0f); a3[m] = (f32x4)(0.0f);
  }
#pragma unroll
  for (int kb = 0; kb < 8; ++kb) {
    bf16x8 B1 = bfrag(WL, mo1, 256, lane, kb);
    bf16x8 B2 = bfrag(WL, mo2, 256, lane, kb);
    bf16x8 B3 = bfrag(WL, mo3, 256, lane, kb);
#pragma unroll
    for (int m = 0; m < MT; ++m) {
      bf16x8 Ah = afrag2(A, m, lane, kb, 0);
      bf16x8 Al = afrag2(A, m, lane, kb, 1);
      a1[m] = mfma16(Ah, B1, a1[m]); a1[m] = mfma16(Al, B1, a1[m]);
      a2[m] = mfma16(Ah, B2, a2[m]); a2[m] = mfma16(Al, B2, a2[m]);
      a3[m] = mfma16(Ah, B3, a3[m]); a3[m] = mfma16(Al, B3, a3[m]);
    }
  }
}

// ch0: A = [x(256) | h_hi | h_lo], W0 slice has K=512; h_lo reuses k 256..511 B-frags.
__device__ __forceinline__ void gemmA(const float* X, int t, int rbase, const __bf16* Hb,
                                      const __bf16* WL, int lane, f32x4 acc[MT]) {
#pragma unroll
  for (int m = 0; m < MT; ++m) acc[m] = (f32x4)(0.0f);
#pragma unroll
  for (int kb = 0; kb < 8; ++kb) {
    bf16x8 B = bfrag(WL, 0, 512, lane, kb);
#pragma unroll
    for (int m = 0; m < MT; ++m) acc[m] = mfma16(xfrag(X, t, rbase, m, lane, kb), B, acc[m]);
  }
#pragma unroll
  for (int kb = 8; kb < 16; ++kb) {
    bf16x8 B = bfrag(WL, 0, 512, lane, kb);
#pragma unroll
    for (int m = 0; m < MT; ++m) {
      bf16x8 Ah = afrag2(Hb, m, lane, kb - 8, 0);
      bf16x8 Al = afrag2(Hb, m, lane, kb - 8, 1);
      acc[m] = mfma16(Ah, B, acc[m]);
      acc[m] = mfma16(Al, B, acc[m]);
    }
  }
}

// acc cols: lane nl<8 holds c-part, nl>=8 holds h-part of the same state col.
// shfl_xor(8) pairs them; both lane halves compute s; hi lanes write bf16(s),
// lo lanes write the residual.
template <int ACT, bool WRITE, bool KEEP, bool MEAN>
__device__ __forceinline__ void finish(const f32x4 acc[MT], const float sp[MT][4],
                                       float so[MT][4], float ma[MT][4], __bf16* sb,
                                       int lane, int cw) {
  const int nl = lane & 15;
  const bool hihalf = nl < 8;
#pragma unroll
  for (int m = 0; m < MT; ++m) {
#pragma unroll
    for (int j = 0; j < 4; ++j) {
      float v = acc[m][j];
      float o = __shfl_xor(v, 8);
      float cpart = hihalf ? v : o;
      float hpart = hihalf ? o : v;
      float s = sp[m][j] + fsig(cpart) * (actf<ACT>(hpart) - sp[m][j]);
      if (MEAN) ma[m][j] += s;
      if (KEEP) so[m][j] = s;
      if (WRITE) {
        int row = m * 16 + ((lane >> 4) << 2) + j;
        int el = ((row >> 2) << 11) + (cw << 6) + ((row & 3) << 4) + (nl & 8) + (nl & 7);
        __bf16 hb_ = (__bf16)s;
        sb[el] = hihalf ? hb_ : (__bf16)(s - (float)hb_);
      }
    }
  }
}

// Monotonic-count barrier among the CWS WGs of one row-group.
__device__ __forceinline__ void gbar(int* cnt, int* gen, int target) {
  __builtin_amdgcn_fence(__ATOMIC_RELEASE, "agent");
  if (threadIdx.x == 0) {
    int old = __hip_atomic_fetch_add(cnt, 1, __ATOMIC_RELAXED, __HIP_MEMORY_SCOPE_AGENT);
    if (old == target * CWS - 1) {
      __builtin_amdgcn_fence(__ATOMIC_ACQUIRE, "agent");
      __hip_atomic_store(gen, target, __ATOMIC_RELEASE, __HIP_MEMORY_SCOPE_AGENT);
    }
  }
  while (__hip_atomic_load(gen, __ATOMIC_RELAXED, __HIP_MEMORY_SCOPE_AGENT) < target) {
    __builtin_amdgcn_s_sleep(1);
  }
  __builtin_amdgcn_fence(__ATOMIC_ACQUIRE, "agent");
}

// Transpose/convert weights to per-col-WG [n][k] bf16 slices; init Hbuf hi/lo
// from Hin; zero barrier counters (every call -> deterministic replays).
__global__ void prep(const float* __restrict__ W0, const float* __restrict__ Ws,
                     const float* __restrict__ Hin, __bf16* __restrict__ wt,
                     __bf16* __restrict__ Hb, int* __restrict__ bar) {
  int gid = blockIdx.x * 256 + threadIdx.x;
  if (gid < WT_TOTAL) {
    int cw = gid / WT_PER_CW;
    int wi = gid - cw * WT_PER_CW;
    int nl, k;
    float v;
    if (wi < 8192) {
      nl = wi >> 9; k = wi & 511;
      int n = cw * 8 + (nl & 7) + ((nl & 8) << 5);
      v = W0[k * 512 + n];
    } else {
      int w2 = wi - 8192;
      int mm = w2 >> 12;
      nl = (w2 >> 8) & 15; k = w2 & 255;
      int n = cw * 8 + (nl & 7) + ((nl & 8) << 5);
      v = Ws[(mm * 256 + k) * 512 + n];
    }
    wt[gid] = (__bf16)v;
  } else if (gid < WT_TOTAL + HB_TOTAL) {
    int el = gid - WT_TOTAL;
    int g = el >> 15;
    int r2 = el & 32767;
    int row = ((r2 >> 11) << 2) + ((r2 >> 4) & 3);
    int cwi = (r2 >> 6) & 31;
    int c = r2 & 15;
    float v = Hin[(g * ROWS_G + row) * 256 + cwi * 8 + (c & 7)];
    __bf16 h = (__bf16)v;
    Hb[el] = (c < 8) ? h : (__bf16)(v - (float)h);
  } else if (gid < WT_TOTAL + HB_TOTAL + 256) {
    bar[gid - WT_TOTAL - HB_TOTAL] = 0;
  }
}

__global__ __launch_bounds__(64) void darts_dist(
    const float* __restrict__ X, const float* __restrict__ Hin,
    const __bf16* __restrict__ wt, __bf16* __restrict__ SB, __bf16* __restrict__ Hb,
    int* __restrict__ bar, float* __restrict__ out) {
  __shared__ __bf16 WL[WT_PER_CW];  // 80 KB: this WG's slice of all 9 matrices
  const int lane = threadIdx.x;
  const int g = blockIdx.x & (GROUPS - 1);
  const int cw = blockIdx.x >> 2;
  const int rbase = g * ROWS_G;
  __bf16* SBg = SB + g * SB_PER_G;
  __bf16* Hbg = Hb + g * HB_PER_G;
  int* cnt = bar + g * 64;
  int* gen = cnt + 32;
  const __bf16* wsl = wt + cw * WT_PER_CW;

  for (int i = lane * 8; i < WT_PER_CW; i += 64 * 8) {
    int moff, K, nl, k;
    if (i < 8192) { moff = 0; K = 512; nl = i >> 9; k = i & 511; }
    else { int w2 = i - 8192; moff = 8192 + ((w2 >> 12) << 12); K = 256; nl = (w2 >> 8) & 15; k = w2 & 255; }
    *(bf16x8*)((char*)WL + wl_byte(moff, K, nl, k)) = *(const bf16x8*)(wsl + i);
  }
  __syncthreads();

  const int nl = lane & 15;
  const int sc = cw * 8 + (nl & 7);
  float hp[MT][4];
#pragma unroll
  for (int m = 0; m < MT; ++m)
#pragma unroll
    for (int j = 0; j < 4; ++j) {
      int row = rbase + m * 16 + ((lane >> 4) << 2) + j;
      hp[m][j] = Hin[row * 256 + sc];
    }

  float s0[MT][4], st1[MT][4], st2[MT][4], st3[MT][4], st5[MT][4], ma[MT][4], dmy[MT][4];
  int bk = 0;
  __bf16* SB0 = SBg;
  __bf16* SB1 = SBg + SB_SLOT;
  __bf16* SB2 = SBg + 2 * SB_SLOT;
  __bf16* SB3 = SBg + 3 * SB_SLOT;
  __bf16* SB4 = SBg + 4 * SB_SLOT;

  for (int t = 0; t < TT; ++t) {
    // Stage A: ch0 -> s0
    f32x4 acc[MT];
    gemmA(X, t, rbase, Hbg, WL, lane, acc);
    finish<2, true, true, false>(acc, hp, s0, ma, SB0, lane, cw);
    gbar(cnt, gen, ++bk);

    // Stage B: states[1] = sig-gate(s0 @ Ws0)
#pragma unroll
    for (int m = 0; m < MT; ++m)
#pragma unroll
      for (int j = 0; j < 4; ++j) ma[m][j] = 0.0f;
    gemm1(SB0, WL, 8192 + 0 * 4096, lane, acc);
    finish<0, true, true, true>(acc, s0, st1, ma, SB1, lane, cw);
    gbar(cnt, gen, ++bk);

    // Stage C: states[2],[3] (relu), [4] (identity) from s1
    f32x4 a2[MT], a3[MT], a4[MT];
    gemm3(SB1, WL, 8192 + 1 * 4096, 8192 + 2 * 4096, 8192 + 3 * 4096, lane, a2, a3, a4);
    finish<1, true, true, true>(a2, st1, st2, ma, SB2, lane, cw);
    finish<1, true, true, true>(a3, st1, st3, ma, SB3, lane, cw);
    finish<3, false, false, true>(a4, st1, dmy, ma, SB0, lane, cw);
    gbar(cnt, gen, ++bk);

    // Stage D: states[5] = tanh(s2 @ Ws4); states[7] = tanh(s3 @ Ws6)
    gemm1(SB2, WL, 8192 + 4 * 4096, lane, acc);
    finish<2, true, true, true>(acc, st2, st5, ma, SB4, lane, cw);
    gemm1(SB3, WL, 8192 + 6 * 4096, lane, acc);
    finish<2, false, false, true>(acc, st3, dmy, ma, SB0, lane, cw);
    gbar(cnt, gen, ++bk);

    // Stage E: states[6] = sig(s5 @ Ws5); states[8] = relu(s5 @ Ws7)
    f32x4 a6[MT], a8[MT];
    gemm2(SB4, WL, 8192 + 5 * 4096, 8192 + 7 * 4096, lane, a6, a8);
    finish<0, false, false, true>(a6, st5, dmy, ma, SB0, lane, cw);
    finish<1, false, false, true>(a8, st5, dmy, ma, SB0, lane, cw);

    // h = mean(states 1..8); write Hbuf hi/lo + out[t]
#pragma unroll
    for (int m = 0; m < MT; ++m)
#pragma unroll
      for (int j = 0; j < 4; ++j) {
        hp[m][j] = ma[m][j] * 0.125f;
        int rloc = m * 16 + ((lane >> 4) << 2) + j;
        int el = ((rloc >> 2) << 11) + (cw << 6) + ((rloc & 3) << 4) + (nl & 8) + (nl & 7);
        __bf16 hb_ = (__bf16)hp[m][j];
        Hbg[el] = (nl < 8) ? hb_ : (__bf16)(hp[m][j] - (float)hb_);
        if (nl < 8) {
          out[((size_t)t * BB + rbase + rloc) * 256 + sc] = hp[m][j];
          if (t == TT - 1)
            out[(size_t)TT * BB * 256 + (size_t)(rbase + rloc) * 256 + sc] = hp[m][j];
        }
      }
    gbar(cnt, gen, ++bk);
  }
}

extern "C" void kernel_launch(void* const* d_in, const int* in_sizes, int n_in,
                              void* d_out, int out_size, void* d_ws, size_t ws_size,
                              hipStream_t stream) {
  (void)in_sizes; (void)n_in; (void)out_size; (void)ws_size;
  const float* X = (const float*)d_in[0];
  const float* Hin = (const float*)d_in[1];
  const float* W0 = (const float*)d_in[2];
  const float* Ws = (const float*)d_in[3];
  __bf16* wt = (__bf16*)d_ws;
  __bf16* SB = wt + WT_TOTAL;
  __bf16* Hb = SB + SB_TOTAL;
  int* bar = (int*)(Hb + HB_TOTAL);
  float* out = (float*)d_out;

  const int prep_total = WT_TOTAL + HB_TOTAL + 256;
  prep<<<(prep_total + 255) / 256, 256, 0, stream>>>(W0, Ws, Hin, wt, Hb, bar);
  darts_dist<<<GROUPS * CWS, 64, 0, stream>>>(X, Hin, wt, SB, Hb, bar, out);
}

// Round 3
// 28938.800 us; speedup vs baseline: 1.0569x; 1.0569x over previous
//
#include <hip/hip_runtime.h>

#define TT 256
#define BB 256
#define NTH 512
#define RNG 8           // ring depth (1KB blocks) per wave
#define SPW 320         // stream blocks per wave per timestep (64 W0 + 8*32 Ws)

typedef __attribute__((ext_vector_type(8))) __bf16 bf16x8;
typedef __attribute__((ext_vector_type(4))) float f32x4;
typedef __attribute__((address_space(1))) const void GAS;
typedef __attribute__((address_space(3))) void LAS;

__device__ __forceinline__ float fsig(float x) { return 1.0f / (1.0f + __expf(-x)); }
__device__ __forceinline__ float ftanh(float x) {
  float e = __expf(-2.0f * fabsf(x));
  float r = (1.0f - e) / (1.0f + e);
  return copysignf(r, x);
}
template <int ACT>
__device__ __forceinline__ float actf(float x) {
  if (ACT == 0) return fsig(x);
  if (ACT == 1) return fmaxf(x, 0.0f);
  if (ACT == 2) return ftanh(x);
  return x;  // identity
}

__device__ __forceinline__ f32x4 mfma16(bf16x8 a, bf16x8 b, f32x4 c) {
  return __builtin_amdgcn_mfma_f32_16x16x32_bf16(a, b, c, 0, 0, 0);
}

// State-LDS addressing with XOR swizzle (round-1 verified).
__device__ __forceinline__ int lds_byte(int stride, int row, int col) {
  return row * stride * 2 + ((col * 2) ^ ((row & 7) << 4));
}
__device__ __forceinline__ bf16x8 lds_frag(const __bf16* base, int stride, int row, int col) {
  return *(const bf16x8*)((const char*)base + lds_byte(stride, row, col));
}
__device__ __forceinline__ void lds_put(__bf16* base, int stride, int row, int col, __bf16 v) {
  *(__bf16*)((char*)base + lds_byte(stride, row, col)) = v;
}

// State slot [16][512]: cols 0..255 hi, 256..511 lo residual.
__device__ __forceinline__ void write_state(__bf16* S, int lrow, int ncol, int scol0,
                                            const float* a, const float* b) {
#pragma unroll
  for (int j = 0; j < 4; ++j) {
    int r = lrow + j;
    __bf16 h0 = (__bf16)a[j];
    lds_put(S, 512, r, scol0 + ncol, h0);
    lds_put(S, 512, r, 256 + scol0 + ncol, (__bf16)(a[j] - (float)h0));
    __bf16 h1 = (__bf16)b[j];
    lds_put(S, 512, r, scol0 + 16 + ncol, h1);
    lds_put(S, 512, r, 256 + scol0 + 16 + ncol, (__bf16)(b[j] - (float)h1));
  }
}

// h into A0 cols 256..511 (hi) / 512..767 (lo).
__device__ __forceinline__ void stage_h(__bf16* A0, int lrow, int ncol, int scol0,
                                        const float* a, const float* b) {
#pragma unroll
  for (int j = 0; j < 4; ++j) {
    int r = lrow + j;
    __bf16 h0 = (__bf16)a[j];
    lds_put(A0, 768, r, 256 + scol0 + ncol, h0);
    lds_put(A0, 768, r, 512 + scol0 + ncol, (__bf16)(a[j] - (float)h0));
    __bf16 h1 = (__bf16)b[j];
    lds_put(A0, 768, r, 256 + scol0 + 16 + ncol, h1);
    lds_put(A0, 768, r, 512 + scol0 + 16 + ncol, (__bf16)(b[j] - (float)h1));
  }
}

__device__ __forceinline__ void barrier_ws() {
  // raw barrier: flush LDS writes, do NOT drain vmcnt (keeps weight ring in flight)
  asm volatile("s_waitcnt lgkmcnt(0)" ::: "memory");
  __builtin_amdgcn_s_barrier();
  __builtin_amdgcn_sched_barrier(0);
}

// Issue one 1KB weight block: global (pre-permuted lane-order) -> ring slot.
__device__ __forceinline__ void wissue(const __bf16* wsrc, __bf16* ring, int& spos, int& slot,
                                       int lane) {
  const __bf16* gp = wsrc + spos * 512 + lane * 8;
  __builtin_amdgcn_global_load_lds((GAS*)gp, (LAS*)(ring + slot * 512), 16, 0, 0);
  spos = (spos + 1 == SPW) ? 0 : spos + 1;
  slot = (slot + 1) & (RNG - 1);
}

// Wait for oldest ring block (vmcnt(7) => all but newest 7 vm-ops retired, so the
// block issued RNG ago is in LDS), then read this wave's lane-linear fragment.
__device__ __forceinline__ bf16x8 wread(const __bf16* ring, int slot, int lane) {
  asm volatile("s_waitcnt vmcnt(7)" ::: "memory");
  return *(const bf16x8*)(ring + slot * 512 + lane * 8);
}

// Issue x-row loads (f32) for step t into XF via global_load_lds (stays in the
// counted vmcnt stream; no compiler-tracked loads).
__device__ __forceinline__ void xf_issue(const float* X, int t, int rb, int wv, int lane,
                                         float* XF) {
#pragma unroll
  for (int q = 0; q < 2; ++q) {
    int r = wv * 2 + q;
    const float* gp = X + ((size_t)t * BB + rb + r) * 256 + lane * 4;
    __builtin_amdgcn_global_load_lds((GAS*)gp, (LAS*)(XF + r * 256), 16, 0, 0);
  }
}

// One genotype GEMM stage (K=256): consume 32 blocks (kb-major, g-inner), A from state slot.
__device__ __forceinline__ void stageW(const __bf16* Sp, const __bf16* wsrc, __bf16* ring,
                                       int& spos, int& slot, int lane, int arow, int kg,
                                       f32x4 acc[4]) {
#pragma unroll
  for (int i = 0; i < 4; ++i) acc[i] = (f32x4)(0.0f);
#pragma unroll
  for (int kb = 0; kb < 8; ++kb) {
    bf16x8 Ah = lds_frag(Sp, 512, arow, kb * 32 + kg);
    bf16x8 Al = lds_frag(Sp, 512, arow, 256 + kb * 32 + kg);
#pragma unroll
    for (int g = 0; g < 4; ++g) {
      bf16x8 B = wread(ring, slot, lane);
      acc[g] = mfma16(Ah, B, acc[g]);
      acc[g] = mfma16(Al, B, acc[g]);
      wissue(wsrc, ring, spos, slot, lane);
    }
  }
}

// W0 stage (K=512): kb 0..7 = x (single A), kb 8..15 = h hi/lo.
__device__ __forceinline__ void stageA(const __bf16* A0, const __bf16* wsrc, __bf16* ring,
                                       int& spos, int& slot, int lane, int arow, int kg,
                                       f32x4 acc[4]) {
#pragma unroll
  for (int i = 0; i < 4; ++i) acc[i] = (f32x4)(0.0f);
#pragma unroll
  for (int kb = 0; kb < 16; ++kb) {
    bf16x8 Ah = lds_frag(A0, 768, arow, kb * 32 + kg);
    bf16x8 Al;
    if (kb >= 8) Al = lds_frag(A0, 768, arow, 256 + kb * 32 + kg);
#pragma unroll
    for (int g = 0; g < 4; ++g) {
      bf16x8 B = wread(ring, slot, lane);
      acc[g] = mfma16(Ah, B, acc[g]);
      if (kb >= 8) acc[g] = mfma16(Al, B, acc[g]);
      wissue(wsrc, ring, spos, slot, lane);
    }
  }
}

template <int ACT>
__device__ __forceinline__ void epi(const f32x4 acc[4], const float* spa, const float* spb,
                                    float* na, float* nb, float* ma, float* mb, __bf16* Sout,
                                    int lrow, int ncol, int scol0) {
  float ta[4], tb[4];
#pragma unroll
  for (int j = 0; j < 4; ++j) {
    float c0 = fsig(acc[0][j]);
    float h0 = actf<ACT>(acc[2][j]);
    ta[j] = spa[j] + c0 * (h0 - spa[j]);
    float c1 = fsig(acc[1][j]);
    float h1 = actf<ACT>(acc[3][j]);
    tb[j] = spb[j] + c1 * (h1 - spb[j]);
    if (ma) { ma[j] += ta[j]; mb[j] += tb[j]; }
  }
  if (na) {
#pragma unroll
    for (int j = 0; j < 4; ++j) { na[j] = ta[j]; nb[j] = tb[j]; }
  }
  if (Sout) write_state(Sout, lrow, ncol, scol0, ta, tb);
}

// Pre-permute weights into per-wave lane-order block streams:
// wt[wv][blk][512], blk order = stage {W0, Ws0, Ws1, Ws2, Ws3, Ws4, Ws6, Ws5, Ws7},
// within stage kb-major, g-inner; block = [lane l][8 el]: row n0+(l&15), k = kb*32+(l>>4)*8+e.
__global__ void prep(const float* __restrict__ W0, const float* __restrict__ Ws,
                     __bf16* __restrict__ wt) {
  int b = blockIdx.x;  // 5120 = 8 waves * 320 blocks * 2 halves
  int wv = b / 640;
  int r = b - wv * 640;
  int blk = r >> 1;
  int el = (r & 1) * 256 + threadIdx.x;  // 0..511
  int l = el >> 3, e = el & 7;
  int s, kb, g;
  if (blk < 64) { s = 0; kb = blk >> 2; g = blk & 3; }
  else { int q = blk - 64; s = 1 + (q >> 5); int w = q & 31; kb = w >> 2; g = w & 3; }
  int n = wv * 32 + (g & 1) * 16 + ((g >> 1) << 8) + (l & 15);
  int k = kb * 32 + ((l >> 4) << 3) + e;
  float v;
  if (s == 0) {
    v = W0[k * 512 + n];
  } else {
    const int mi[9] = {0, 0, 1, 2, 3, 4, 6, 5, 7};
    v = Ws[((size_t)mi[s] * 256 + k) * 512 + n];
  }
  wt[(size_t)wv * (SPW * 512) + blk * 512 + el] = (__bf16)v;
}

__global__ __launch_bounds__(NTH) void darts3(const float* __restrict__ X,
                                              const float* __restrict__ Hin,
                                              const __bf16* __restrict__ WT,
                                              float* __restrict__ out) {
  __shared__ __bf16 RING[8][RNG * 512];  // 64KB: per-wave weight rings
  __shared__ float XF[16 * 256];          // 16KB: x_t staging (f32)
  __shared__ __bf16 A0[16 * 768];         // 24KB: [x bf16 | h hi | h lo]
  __shared__ __bf16 SBa[16 * 512], SBb[16 * 512], SBc[16 * 512];  // 48KB states

  const int tid = threadIdx.x, lane = tid & 63, wv = tid >> 6;
  const int scol0 = wv * 32, lrow = (lane >> 4) * 4, ncol = lane & 15;
  const int arow = lane & 15, kg = (lane >> 4) * 8;
  const int rb = blockIdx.x * 16;
  const __bf16* wsrc = WT + (size_t)wv * (SPW * 512);
  __bf16* ring = RING[wv];
  int spos = 0, slot = 0;

  float hpa[4], hpb[4];
#pragma unroll
  for (int j = 0; j < 4; ++j) {
    hpa[j] = Hin[(rb + lrow + j) * 256 + scol0 + ncol];
    hpb[j] = Hin[(rb + lrow + j) * 256 + scol0 + 16 + ncol];
  }
  stage_h(A0, lrow, ncol, scol0, hpa, hpb);

  // prologue: x(t=0) + fill ring
  xf_issue(X, 0, rb, wv, lane, XF);
#pragma unroll
  for (int i = 0; i < RNG; ++i) wissue(wsrc, ring, spos, slot, lane);

  float s0a[4], s0b[4], s1a[4], s1b[4], s2a[4], s2b[4], s3a[4], s3b[4], s5a[4], s5b[4];
  float ma[4], mb[4];
  f32x4 acc[4];

  for (int t = 0; t < TT; ++t) {
    // --- step top: materialize x into A0 (bf16) ---
    asm volatile("s_waitcnt vmcnt(7)" ::: "memory");  // own XF rows retired
    barrier_ws();                                      // everyone's XF retired
    {
      int r = tid >> 5, c = (tid & 31) * 8;
      const float* xp = XF + r * 256 + c;
      float4 v0 = *(const float4*)xp;
      float4 v1 = *(const float4*)(xp + 4);
      bf16x8 pk;
      pk[0] = (__bf16)v0.x; pk[1] = (__bf16)v0.y; pk[2] = (__bf16)v0.z; pk[3] = (__bf16)v0.w;
      pk[4] = (__bf16)v1.x; pk[5] = (__bf16)v1.y; pk[6] = (__bf16)v1.z; pk[7] = (__bf16)v1.w;
      *(bf16x8*)((char*)A0 + lds_byte(768, r, c)) = pk;
    }
    barrier_ws();

    // --- Stage A: ch0 -> s0 (tanh) ---
    stageA(A0, wsrc, ring, spos, slot, lane, arow, kg, acc);
    epi<2>(acc, hpa, hpb, s0a, s0b, nullptr, nullptr, SBa, lrow, ncol, scol0);
    barrier_ws();

#pragma unroll
    for (int j = 0; j < 4; ++j) { ma[j] = 0.f; mb[j] = 0.f; }

    // --- Stage B: s1 = sigmoid-step(s0 @ Ws0) ---
    stageW(SBa, wsrc, ring, spos, slot, lane, arow, kg, acc);
    epi<0>(acc, s0a, s0b, s1a, s1b, ma, mb, SBb, lrow, ncol, scol0);
    barrier_ws();

    // --- Stage C: s2 (relu), s3 (relu), s4 (identity) from s1 ---
    stageW(SBb, wsrc, ring, spos, slot, lane, arow, kg, acc);
    epi<1>(acc, s1a, s1b, s2a, s2b, ma, mb, SBa, lrow, ncol, scol0);
    stageW(SBb, wsrc, ring, spos, slot, lane, arow, kg, acc);
    epi<1>(acc, s1a, s1b, s3a, s3b, ma, mb, SBc, lrow, ncol, scol0);
    stageW(SBb, wsrc, ring, spos, slot, lane, arow, kg, acc);
    epi<3>(acc, s1a, s1b, nullptr, nullptr, ma, mb, nullptr, lrow, ncol, scol0);
    barrier_ws();

    // --- Stage D: s5 = tanh(s2 @ Ws4); s7 = tanh(s3 @ Ws6) ---
    stageW(SBa, wsrc, ring, spos, slot, lane, arow, kg, acc);
    epi<2>(acc, s2a, s2b, s5a, s5b, ma, mb, SBb, lrow, ncol, scol0);
    stageW(SBc, wsrc, ring, spos, slot, lane, arow, kg, acc);
    epi<2>(acc, s3a, s3b, nullptr, nullptr, ma, mb, nullptr, lrow, ncol, scol0);
    barrier_ws();

    // prefetch next x (stays ahead of stage E's 64 block-issues)
    if (t + 1 < TT) xf_issue(X, t + 1, rb, wv, lane, XF);

    // --- Stage E: s6 = sig(s5 @ Ws5); s8 = relu(s5 @ Ws7) ---
    stageW(SBb, wsrc, ring, spos, slot, lane, arow, kg, acc);
    epi<0>(acc, s5a, s5b, nullptr, nullptr, ma, mb, nullptr, lrow, ncol, scol0);
    stageW(SBb, wsrc, ring, spos, slot, lane, arow, kg, acc);
    epi<1>(acc, s5a, s5b, nullptr, nullptr, ma, mb, nullptr, lrow, ncol, scol0);

    // --- h = mean(states 1..8); store hiddens[t]; restage h ---
#pragma unroll
    for (int j = 0; j < 4; ++j) { hpa[j] = ma[j] * 0.125f; hpb[j] = mb[j] * 0.125f; }
#pragma unroll
    for (int j = 0; j < 4; ++j) {
      size_t base = ((size_t)t * BB + rb + lrow + j) * 256;
      out[base + scol0 + ncol] = hpa[j];
      out[base + scol0 + 16 + ncol] = hpb[j];
    }
    if (t == TT - 1) {
#pragma unroll
      for (int j = 0; j < 4; ++j) {
        size_t base = ((size_t)TT * BB + rb + lrow + j) * 256;
        out[base + scol0 + ncol] = hpa[j];
        out[base + scol0 + 16 + ncol] = hpb[j];
      }
    }
    stage_h(A0, lrow, ncol, scol0, hpa, hpb);
  }
  asm volatile("s_waitcnt vmcnt(0)" ::: "memory");  // drain tail gll before endpgm
}

extern "C" void kernel_launch(void* const* d_in, const int* in_sizes, int n_in,
                              void* d_out, int out_size, void* d_ws, size_t ws_size,
                              hipStream_t stream) {
  (void)in_sizes; (void)n_in; (void)out_size; (void)ws_size;
  const float* X = (const float*)d_in[0];
  const float* Hin = (const float*)d_in[1];
  const float* W0 = (const float*)d_in[2];
  const float* Ws = (const float*)d_in[3];
  __bf16* wt = (__bf16*)d_ws;  // 8 waves * 320 blocks * 512 bf16 = 2.62 MB
  float* out = (float*)d_out;

  prep<<<5120, 256, 0, stream>>>(W0, Ws, wt);
  darts3<<<16, NTH, 0, stream>>>(X, Hin, wt, out);
}

// Round 4
// 10524.014 us; speedup vs baseline: 2.9063x; 2.7498x over previous
//
#include <hip/hip_runtime.h>

#define TT 256
#define BB 256
#define NTH 512
#define SW 3100.0f

typedef __attribute__((ext_vector_type(4))) int i32x4;

__device__ __forceinline__ float fsig(float x) { return 1.0f / (1.0f + __expf(-x)); }
__device__ __forceinline__ float ftanh(float x) {
  float e = __expf(-2.0f * fabsf(x));
  float r = (1.0f - e) / (1.0f + e);
  return copysignf(r, x);
}
template <int ACT>
__device__ __forceinline__ float actf(float x) {
  if (ACT == 0) return fsig(x);
  if (ACT == 1) return fmaxf(x, 0.0f);
  if (ACT == 2) return ftanh(x);
  return x;  // identity
}

__device__ __forceinline__ i32x4 mi8(i32x4 a, i32x4 b, i32x4 c) {
  return __builtin_amdgcn_mfma_i32_16x16x64_i8(a, b, c, 0, 0, 0);
}

// [16][256] int8 plane, XOR-swizzled: 16 rows at fixed k would otherwise hit the
// same bank-quad on ds_read_b128 (stride 256B).
__device__ __forceinline__ int swz(int row, int k) { return row * 256 + (k ^ ((row & 7) << 4)); }

__device__ __forceinline__ i32x4 afrag(const char* P, int lane, int kbase) {
  int row = lane & 15;
  int k0 = kbase + ((lane >> 4) << 4);
  return *(const i32x4*)(P + swz(row, k0));
}

__device__ __forceinline__ int clampc(float v) {
  return (int)rintf(fminf(fmaxf(v, -127.0f), 127.0f));
}
__device__ __forceinline__ int pack4(int a, int b, int c, int d) {
  return (a & 255) | ((b & 255) << 8) | ((c & 255) << 16) | ((d & 255) << 24);
}

// hi/lo int8 state quantization: s = hi/32 + lo/4096 (+/- 2^-13)
__device__ __forceinline__ void put_sv(char* HI, char* LO, int row, int col, float s) {
  int hi = clampc(s * 32.0f);
  float r = s - (float)hi * (1.0f / 32.0f);
  int lo = clampc(r * 4096.0f);
  int a = swz(row, col);
  HI[a] = (char)hi;
  LO[a] = (char)lo;
}

// Genotype GEMM: K=256, acc tiles at wave n-offsets {0,16} (c-part) and {256,256+16} (h-part).
__device__ __forceinline__ void ggemm(const char* SHp, const char* SLp, const char* wb,
                                      int lane, i32x4* ah, i32x4* al) {
#pragma unroll
  for (int n = 0; n < 4; ++n) { ah[n] = (i32x4)(0); al[n] = (i32x4)(0); }
#pragma unroll
  for (int kt = 0; kt < 4; ++kt) {
    i32x4 Ah = afrag(SHp, lane, kt * 64);
    i32x4 Al = afrag(SLp, lane, kt * 64);
#pragma unroll
    for (int n = 0; n < 4; ++n) {
      i32x4 B = *(const i32x4*)(wb + (kt * 4 + n) * 1024 + lane * 16);
      ah[n] = mi8(Ah, B, ah[n]);
      al[n] = mi8(Al, B, al[n]);
    }
  }
}

template <int ACT>
__device__ __forceinline__ void gepi(const i32x4* ah, const i32x4* al, const float* spa,
                                     const float* spb, float* na, float* nb, float* ma,
                                     float* mb, char* SH, char* SL, int lrow, int ncol,
                                     int scol0) {
  const float INVG = 1.0f / (4096.0f * SW);
#pragma unroll
  for (int j = 0; j < 4; ++j) {
    float cA = ((float)ah[0][j] * 128.0f + (float)al[0][j]) * INVG;
    float hA = ((float)ah[2][j] * 128.0f + (float)al[2][j]) * INVG;
    float sA = spa[j] + fsig(cA) * (actf<ACT>(hA) - spa[j]);
    float cB = ((float)ah[1][j] * 128.0f + (float)al[1][j]) * INVG;
    float hB = ((float)ah[3][j] * 128.0f + (float)al[3][j]) * INVG;
    float sB = spb[j] + fsig(cB) * (actf<ACT>(hB) - spb[j]);
    ma[j] += sA;
    mb[j] += sB;
    if (na) { na[j] = sA; nb[j] = sB; }
    if (SH) {
      put_sv(SH, SL, lrow + j, scol0 + ncol, sA);
      put_sv(SH, SL, lrow + j, scol0 + 16 + ncol, sB);
    }
  }
}

// Quantize + permute weights into per-wave lane-ordered int8 block streams.
// wq[wv][blk 0..159][lane][16]: blk 0-15 = W0 x-part (kt*4+nt), 16-31 = W0 h-part,
// 32+s*16+kt*4+nt = genotype stage s in consumption order Ws{0,1,2,3,4,6,5,7}.
// wlo[wv][blk 0..15]: W0 x-part residual (int8, scale SW*128), register-parked.
__global__ void prep(const float* __restrict__ W0, const float* __restrict__ Ws,
                     char* __restrict__ wq, char* __restrict__ wlo) {
  int gid = blockIdx.x * 256 + threadIdx.x;
  const int mi[8] = {0, 1, 2, 3, 4, 6, 5, 7};
  if (gid < 1310720) {
    int wv = gid / 163840;
    int r = gid - wv * 163840;
    int blk = r >> 10, b = r & 1023;
    int l = b >> 4, e = b & 15;
    int kloc = ((l >> 4) << 4) + e;
    int nt, n, k;
    float v;
    if (blk < 32) {
      int part = blk >> 4;  // 0=x rows, 1=h rows of W0
      int q = blk & 15;
      nt = q & 3;
      n = wv * 32 + (nt & 1) * 16 + ((nt >> 1) << 8) + (l & 15);
      k = part * 256 + (q >> 2) * 64 + kloc;
      v = W0[k * 512 + n];
    } else {
      int q = blk - 32;
      int s = q >> 4, w2 = q & 15;
      nt = w2 & 3;
      n = wv * 32 + (nt & 1) * 16 + ((nt >> 1) << 8) + (l & 15);
      k = (w2 >> 2) * 64 + kloc;
      v = Ws[(size_t)mi[s] * 131072 + k * 512 + n];
    }
    wq[gid] = (char)(int)rintf(v * SW);
  } else {
    int i2 = gid - 1310720;
    int wv = i2 >> 14;
    int r = i2 & 16383;
    int blk = r >> 10, b = r & 1023;
    int l = b >> 4, e = b & 15;
    int nt = blk & 3;
    int n = wv * 32 + (nt & 1) * 16 + ((nt >> 1) << 8) + (l & 15);
    int k = (blk >> 2) * 64 + ((l >> 4) << 4) + e;
    float v = W0[k * 512 + n];
    float q = rintf(v * SW);
    float res = v - q * (1.0f / SW);
    wlo[i2] = (char)clampc(res * (SW * 128.0f));
  }
}

__global__ __launch_bounds__(NTH, 2) void darts4(const float* __restrict__ X,
                                                 const float* __restrict__ Hin,
                                                 const char* __restrict__ WQ,
                                                 const char* __restrict__ WLO,
                                                 float* __restrict__ out) {
  __shared__ char A0XH[4096], A0XL[4096], A0HH[4096], A0HL[4096];
  __shared__ char SAH[4096], SAL[4096], SBH[4096], SBL[4096], SCH[4096], SCL[4096];

  const int tid = threadIdx.x, lane = tid & 63, wv = tid >> 6;
  const int scol0 = wv * 32;
  const int lrow = (lane >> 4) << 2, ncol = lane & 15;
  const int rb = blockIdx.x * 16;
  const char* wq = WQ + (size_t)wv * 163840;
  const char* wl = WLO + wv * 16384;

  // park W0-x residual stream in registers (16 KB/wave, loaded once)
  i32x4 WREG[16];
#pragma unroll
  for (int b = 0; b < 16; ++b) WREG[b] = *(const i32x4*)(wl + b * 1024 + lane * 16);

  float hpa[4], hpb[4];
#pragma unroll
  for (int j = 0; j < 4; ++j) {
    hpa[j] = Hin[(rb + lrow + j) * 256 + scol0 + ncol];
    hpb[j] = Hin[(rb + lrow + j) * 256 + scol0 + 16 + ncol];
  }
#pragma unroll
  for (int j = 0; j < 4; ++j) {
    put_sv(A0HH, A0HL, lrow + j, scol0 + ncol, hpa[j]);
    put_sv(A0HH, A0HL, lrow + j, scol0 + 16 + ncol, hpb[j]);
  }

  float s0a[4], s0b[4], s1a[4], s1b[4], s2a[4], s2b[4], s3a[4], s3b[4], s5a[4], s5b[4];
  float ma[4], mb[4];

  for (int t = 0; t < TT; ++t) {
    {  // stage x_t -> int8 hi/lo planes (x = hi/16 + lo/2048)
      int r = tid >> 5, c0 = (tid & 31) * 8;
      const float* xp = X + ((size_t)t * BB + rb + r) * 256 + c0;
      float4 v0 = *(const float4*)xp;
      float4 v1 = *(const float4*)(xp + 4);
      float xs[8] = {v0.x, v0.y, v0.z, v0.w, v1.x, v1.y, v1.z, v1.w};
      int hb[8], lb[8];
#pragma unroll
      for (int j = 0; j < 8; ++j) {
        int hi = clampc(xs[j] * 16.0f);
        float res = xs[j] - (float)hi * (1.0f / 16.0f);
        lb[j] = clampc(res * 2048.0f);
        hb[j] = hi;
      }
      int a = swz(r, c0);
      *(int2*)(A0XH + a) = make_int2(pack4(hb[0], hb[1], hb[2], hb[3]),
                                     pack4(hb[4], hb[5], hb[6], hb[7]));
      *(int2*)(A0XL + a) = make_int2(pack4(lb[0], lb[1], lb[2], lb[3]),
                                     pack4(lb[4], lb[5], lb[6], lb[7]));
    }
    __syncthreads();

    {  // W0 stage: ch0 = [x | h] @ W0 -> s0
      i32x4 xh[4], xl[4], xw[4], hh[4], hl[4];
#pragma unroll
      for (int n = 0; n < 4; ++n) {
        xh[n] = (i32x4)(0); xl[n] = (i32x4)(0); xw[n] = (i32x4)(0);
        hh[n] = (i32x4)(0); hl[n] = (i32x4)(0);
      }
#pragma unroll
      for (int kt = 0; kt < 4; ++kt) {
        i32x4 Axh = afrag(A0XH, lane, kt * 64);
        i32x4 Axl = afrag(A0XL, lane, kt * 64);
#pragma unroll
        for (int n = 0; n < 4; ++n) {
          i32x4 B = *(const i32x4*)(wq + (kt * 4 + n) * 1024 + lane * 16);
          xh[n] = mi8(Axh, B, xh[n]);
          xl[n] = mi8(Axl, B, xl[n]);
          xw[n] = mi8(Axh, WREG[kt * 4 + n], xw[n]);
        }
      }
#pragma unroll
      for (int kt = 0; kt < 4; ++kt) {
        i32x4 Ahh = afrag(A0HH, lane, kt * 64);
        i32x4 Ahl = afrag(A0HL, lane, kt * 64);
#pragma unroll
        for (int n = 0; n < 4; ++n) {
          i32x4 B = *(const i32x4*)(wq + (16 + kt * 4 + n) * 1024 + lane * 16);
          hh[n] = mi8(Ahh, B, hh[n]);
          hl[n] = mi8(Ahl, B, hl[n]);
        }
      }
      const float INVD = 1.0f / (4096.0f * SW);
#pragma unroll
      for (int j = 0; j < 4; ++j) {
        float cA = ((float)xh[0][j] * 256.0f + ((float)xl[0][j] + (float)xw[0][j]) * 2.0f +
                    (float)hh[0][j] * 128.0f + (float)hl[0][j]) * INVD;
        float hA = ((float)xh[2][j] * 256.0f + ((float)xl[2][j] + (float)xw[2][j]) * 2.0f +
                    (float)hh[2][j] * 128.0f + (float)hl[2][j]) * INVD;
        s0a[j] = hpa[j] + fsig(cA) * (ftanh(hA) - hpa[j]);
        float cB = ((float)xh[1][j] * 256.0f + ((float)xl[1][j] + (float)xw[1][j]) * 2.0f +
                    (float)hh[1][j] * 128.0f + (float)hl[1][j]) * INVD;
        float hB = ((float)xh[3][j] * 256.0f + ((float)xl[3][j] + (float)xw[3][j]) * 2.0f +
                    (float)hh[3][j] * 128.0f + (float)hl[3][j]) * INVD;
        s0b[j] = hpb[j] + fsig(cB) * (ftanh(hB) - hpb[j]);
        put_sv(SAH, SAL, lrow + j, scol0 + ncol, s0a[j]);
        put_sv(SAH, SAL, lrow + j, scol0 + 16 + ncol, s0b[j]);
      }
    }
    __syncthreads();

#pragma unroll
    for (int j = 0; j < 4; ++j) { ma[j] = 0.f; mb[j] = 0.f; }

    i32x4 ah[4], al[4];
    // B: s1 = sig step (Ws0) from SA(s0) -> SB
    ggemm(SAH, SAL, wq + 32 * 1024, lane, ah, al);
    gepi<0>(ah, al, s0a, s0b, s1a, s1b, ma, mb, SBH, SBL, lrow, ncol, scol0);
    __syncthreads();

    // C: s2 relu -> SA, s3 relu -> SC, s4 identity (no store), all from SB(s1)
    ggemm(SBH, SBL, wq + 48 * 1024, lane, ah, al);
    gepi<1>(ah, al, s1a, s1b, s2a, s2b, ma, mb, SAH, SAL, lrow, ncol, scol0);
    ggemm(SBH, SBL, wq + 64 * 1024, lane, ah, al);
    gepi<1>(ah, al, s1a, s1b, s3a, s3b, ma, mb, SCH, SCL, lrow, ncol, scol0);
    ggemm(SBH, SBL, wq + 80 * 1024, lane, ah, al);
    gepi<3>(ah, al, s1a, s1b, (float*)nullptr, (float*)nullptr, ma, mb, (char*)nullptr,
            (char*)nullptr, lrow, ncol, scol0);
    __syncthreads();

    // D: s5 tanh (Ws4) from SA(s2) -> SB; s7 tanh (Ws6) from SC(s3), no store
    ggemm(SAH, SAL, wq + 96 * 1024, lane, ah, al);
    gepi<2>(ah, al, s2a, s2b, s5a, s5b, ma, mb, SBH, SBL, lrow, ncol, scol0);
    ggemm(SCH, SCL, wq + 112 * 1024, lane, ah, al);
    gepi<2>(ah, al, s3a, s3b, (float*)nullptr, (float*)nullptr, ma, mb, (char*)nullptr,
            (char*)nullptr, lrow, ncol, scol0);
    __syncthreads();

    // E: s6 sig (Ws5), s8 relu (Ws7), both from SB(s5)
    ggemm(SBH, SBL, wq + 128 * 1024, lane, ah, al);
    gepi<0>(ah, al, s5a, s5b, (float*)nullptr, (float*)nullptr, ma, mb, (char*)nullptr,
            (char*)nullptr, lrow, ncol, scol0);
    ggemm(SBH, SBL, wq + 144 * 1024, lane, ah, al);
    gepi<1>(ah, al, s5a, s5b, (float*)nullptr, (float*)nullptr, ma, mb, (char*)nullptr,
            (char*)nullptr, lrow, ncol, scol0);

    // h = mean(states 1..8); store hiddens[t]; restage h
#pragma unroll
    for (int j = 0; j < 4; ++j) { hpa[j] = ma[j] * 0.125f; hpb[j] = mb[j] * 0.125f; }
#pragma unroll
    for (int j = 0; j < 4; ++j) {
      size_t base = ((size_t)t * BB + rb + lrow + j) * 256;
      out[base + scol0 + ncol] = hpa[j];
      out[base + scol0 + 16 + ncol] = hpb[j];
    }
    if (t == TT - 1) {
#pragma unroll
      for (int j = 0; j < 4; ++j) {
        size_t base = ((size_t)TT * BB + rb + lrow + j) * 256;
        out[base + scol0 + ncol] = hpa[j];
        out[base + scol0 + 16 + ncol] = hpb[j];
      }
    }
#pragma unroll
    for (int j = 0; j < 4; ++j) {
      put_sv(A0HH, A0HL, lrow + j, scol0 + ncol, hpa[j]);
      put_sv(A0HH, A0HL, lrow + j, scol0 + 16 + ncol, hpb[j]);
    }
  }
}

extern "C" void kernel_launch(void* const* d_in, const int* in_sizes, int n_in,
                              void* d_out, int out_size, void* d_ws, size_t ws_size,
                              hipStream_t stream) {
  (void)in_sizes; (void)n_in; (void)out_size; (void)ws_size;
  const float* X = (const float*)d_in[0];
  const float* Hin = (const float*)d_in[1];
  const float* W0 = (const float*)d_in[2];
  const float* Ws = (const float*)d_in[3];
  char* wq = (char*)d_ws;            // 8 waves * 160 blocks * 1024 B = 1.31 MB
  char* wlo = wq + 1310720;          // 8 waves * 16 blocks * 1024 B = 128 KB
  float* out = (float*)d_out;

  prep<<<5632, 256, 0, stream>>>(W0, Ws, wq, wlo);
  darts4<<<16, NTH, 0, stream>>>(X, Hin, wq, wlo, out);
}

// Round 5
// 10468.211 us; speedup vs baseline: 2.9218x; 1.0053x over previous
//
#include <hip/hip_runtime.h>

#define TT 256
#define BB 256
#define SW 3100.0f
#define WSTRIDE 90112  // 88 blocks * 1024 B per wave

typedef __attribute__((ext_vector_type(4))) int i32x4;

__device__ __forceinline__ float fsig(float x) { return 1.0f / (1.0f + __expf(-x)); }
__device__ __forceinline__ float ftanh(float x) {
  float e = __expf(-2.0f * fabsf(x));
  float r = (1.0f - e) / (1.0f + e);
  return copysignf(r, x);
}
template <int ACT>
__device__ __forceinline__ float actf(float x) {
  if (ACT == 0) return fsig(x);
  if (ACT == 1) return fmaxf(x, 0.0f);
  if (ACT == 2) return ftanh(x);
  return x;  // identity
}

__device__ __forceinline__ i32x4 mi8(i32x4 a, i32x4 b, i32x4 c) {
  return __builtin_amdgcn_mfma_i32_16x16x64_i8(a, b, c, 0, 0, 0);
}

// [16][256] int8 plane, XOR-swizzled (verified rounds 1-4).
__device__ __forceinline__ int swz(int row, int k) { return row * 256 + (k ^ ((row & 7) << 4)); }

__device__ __forceinline__ i32x4 afrag(const char* P, int lane, int kbase) {
  int row = lane & 15;
  int k0 = kbase + ((lane >> 4) << 4);
  return *(const i32x4*)(P + swz(row, k0));
}

__device__ __forceinline__ int clampc(float v) {
  return (int)rintf(fminf(fmaxf(v, -127.0f), 127.0f));
}
__device__ __forceinline__ int pack4(int a, int b, int c, int d) {
  return (a & 255) | ((b & 255) << 8) | ((c & 255) << 16) | ((d & 255) << 24);
}

// state s = hi/32 + lo/4096
__device__ __forceinline__ void put_sv(char* HI, char* LO, int row, int col, float s) {
  int hi = clampc(s * 32.0f);
  float r = s - (float)hi * (1.0f / 32.0f);
  int lo = clampc(r * 4096.0f);
  int a = swz(row, col);
  HI[a] = (char)hi;
  LO[a] = (char)lo;
}

// One genotype stage for this wave's 16 state-cols; weights from registers.
template <int ACT, bool KEEP, bool STORE>
__device__ __forceinline__ void gstage(const char* SH, const char* SL, const i32x4 (&w)[8],
                                       const float* sp, float* sn, float* ma, char* OH,
                                       char* OL, int lane, int lrow, int sc) {
  i32x4 ch = (i32x4)(0), cl = (i32x4)(0), hh = (i32x4)(0), hl = (i32x4)(0);
#pragma unroll
  for (int kt = 0; kt < 4; ++kt) {
    i32x4 Ah = afrag(SH, lane, kt * 64);
    i32x4 Al = afrag(SL, lane, kt * 64);
    ch = mi8(Ah, w[kt * 2 + 0], ch);
    hh = mi8(Ah, w[kt * 2 + 1], hh);
    cl = mi8(Al, w[kt * 2 + 0], cl);
    hl = mi8(Al, w[kt * 2 + 1], hl);
  }
  const float INVG = 1.0f / (4096.0f * SW);
#pragma unroll
  for (int j = 0; j < 4; ++j) {
    float c = ((float)ch[j] * 128.0f + (float)cl[j]) * INVG;
    float h = ((float)hh[j] * 128.0f + (float)hl[j]) * INVG;
    float s = sp[j] + fsig(c) * (actf<ACT>(h) - sp[j]);
    ma[j] += s;
    if (KEEP) sn[j] = s;
    if (STORE) put_sv(OH, OL, lrow + j, sc, s);
  }
}

// Quantize + permute weights into per-wave register-block streams.
// Per wave (16 waves, 88 blocks of [lane][16 B]):
//   blk 0..7   W0 x-part hi   (kt*2+nt)
//   blk 8..15  W0 x-part residual (int8, scale SW*128)
//   blk 16..23 W0 h-part hi
//   blk 24+s*8+kt*2+nt : genotype slot s in consumption order Ws{0,1,2,3,4,6,5,7}
// n = nt*256 + wv*16 + (l&15); k = kt*64 + (l>>4)*16 + e.
__global__ void prep(const float* __restrict__ W0, const float* __restrict__ Ws,
                     char* __restrict__ wq) {
  int gid = blockIdx.x * 256 + threadIdx.x;
  const int mi[8] = {0, 1, 2, 3, 4, 6, 5, 7};
  int wv = gid / WSTRIDE;
  int r = gid - wv * WSTRIDE;
  int blk = r >> 10, b = r & 1023;
  int l = b >> 4, e = b & 15;
  int kt = (blk & 7) >> 1, nt = blk & 1;
  int n = nt * 256 + wv * 16 + (l & 15);
  int k = kt * 64 + ((l >> 4) << 4) + e;
  char outb;
  if (blk < 8) {
    float v = W0[k * 512 + n];
    outb = (char)(int)rintf(v * SW);
  } else if (blk < 16) {
    float v = W0[k * 512 + n];
    float q = rintf(v * SW);
    float res = v - q * (1.0f / SW);
    outb = (char)clampc(res * (SW * 128.0f));
  } else if (blk < 24) {
    float v = W0[(256 + k) * 512 + n];
    outb = (char)(int)rintf(v * SW);
  } else {
    int s = (blk - 24) >> 3;
    float v = Ws[(size_t)mi[s] * 131072 + k * 512 + n];
    outb = (char)(int)rintf(v * SW);
  }
  wq[gid] = outb;
}

__global__ __launch_bounds__(1024, 4) void darts5(const float* __restrict__ X,
                                                  const float* __restrict__ Hin,
                                                  const char* __restrict__ WQ,
                                                  float* __restrict__ out) {
  __shared__ char A0XH[4096], A0XL[4096], A0HH[4096], A0HL[4096];
  __shared__ char SAH[4096], SAL[4096], SBH[4096], SBL[4096], SCH[4096], SCL[4096];

  const int tid = threadIdx.x, lane = tid & 63, wv = tid >> 6;  // 16 waves
  const int ncol = lane & 15, lrow = (lane >> 4) << 2;
  const int sc = wv * 16 + ncol;  // this lane's state column
  const int rb = blockIdx.x * 16;

  // ---- park weights in registers (352 VGPRs), loaded once ----
  const char* base = WQ + (size_t)wv * WSTRIDE + lane * 16;
  i32x4 W0X[8], W0R[8], W0H[8], WS[8][8];
#pragma unroll
  for (int i = 0; i < 8; ++i) W0X[i] = *(const i32x4*)(base + i * 1024);
#pragma unroll
  for (int i = 0; i < 8; ++i) W0R[i] = *(const i32x4*)(base + 8192 + i * 1024);
#pragma unroll
  for (int i = 0; i < 8; ++i) W0H[i] = *(const i32x4*)(base + 16384 + i * 1024);
#pragma unroll
  for (int s = 0; s < 8; ++s)
#pragma unroll
    for (int i = 0; i < 8; ++i)
      WS[s][i] = *(const i32x4*)(base + 24576 + s * 8192 + i * 1024);

  float hp[4];
#pragma unroll
  for (int j = 0; j < 4; ++j) hp[j] = Hin[(rb + lrow + j) * 256 + sc];
#pragma unroll
  for (int j = 0; j < 4; ++j) put_sv(A0HH, A0HL, lrow + j, sc, hp[j]);

  float s0[4], s1[4], s2[4], s3[4], s5[4], ma[4], dmy[4];
  const float INVD = 1.0f / (4096.0f * SW);

  for (int t = 0; t < TT; ++t) {
    {  // stage x_t: 1024 threads, 4 cols each; x = hi/16 + lo/2048
      int r = tid >> 6, c0 = (tid & 63) * 4;
      const float* xp = X + ((size_t)t * BB + rb + r) * 256 + c0;
      float4 v = *(const float4*)xp;
      float xs[4] = {v.x, v.y, v.z, v.w};
      int hb[4], lb[4];
#pragma unroll
      for (int j = 0; j < 4; ++j) {
        int hi = clampc(xs[j] * 16.0f);
        float res = xs[j] - (float)hi * (1.0f / 16.0f);
        lb[j] = clampc(res * 2048.0f);
        hb[j] = hi;
      }
      int a = swz(r, c0);
      *(int*)(A0XH + a) = pack4(hb[0], hb[1], hb[2], hb[3]);
      *(int*)(A0XL + a) = pack4(lb[0], lb[1], lb[2], lb[3]);
    }
    __syncthreads();

    {  // W0 stage: ch0 = [x | h] @ W0 -> s0 (residual folded into lo-acc: same coeff 2)
      i32x4 axh[2], alo[2], ahh[2], ahl[2];
#pragma unroll
      for (int nt = 0; nt < 2; ++nt) {
        axh[nt] = (i32x4)(0); alo[nt] = (i32x4)(0);
        ahh[nt] = (i32x4)(0); ahl[nt] = (i32x4)(0);
      }
#pragma unroll
      for (int kt = 0; kt < 4; ++kt) {
        i32x4 Axh = afrag(A0XH, lane, kt * 64);
        i32x4 Axl = afrag(A0XL, lane, kt * 64);
#pragma unroll
        for (int nt = 0; nt < 2; ++nt) {
          axh[nt] = mi8(Axh, W0X[kt * 2 + nt], axh[nt]);
          alo[nt] = mi8(Axl, W0X[kt * 2 + nt], alo[nt]);
          alo[nt] = mi8(Axh, W0R[kt * 2 + nt], alo[nt]);
        }
      }
#pragma unroll
      for (int kt = 0; kt < 4; ++kt) {
        i32x4 Ahh = afrag(A0HH, lane, kt * 64);
        i32x4 Ahl = afrag(A0HL, lane, kt * 64);
#pragma unroll
        for (int nt = 0; nt < 2; ++nt) {
          ahh[nt] = mi8(Ahh, W0H[kt * 2 + nt], ahh[nt]);
          ahl[nt] = mi8(Ahl, W0H[kt * 2 + nt], ahl[nt]);
        }
      }
#pragma unroll
      for (int j = 0; j < 4; ++j) {
        float c = ((float)axh[0][j] * 256.0f + (float)alo[0][j] * 2.0f +
                   (float)ahh[0][j] * 128.0f + (float)ahl[0][j]) * INVD;
        float h = ((float)axh[1][j] * 256.0f + (float)alo[1][j] * 2.0f +
                   (float)ahh[1][j] * 128.0f + (float)ahl[1][j]) * INVD;
        s0[j] = hp[j] + fsig(c) * (ftanh(h) - hp[j]);
        put_sv(SAH, SAL, lrow + j, sc, s0[j]);
      }
    }
    __syncthreads();

#pragma unroll
    for (int j = 0; j < 4; ++j) ma[j] = 0.0f;

    // B: s1 (sigmoid) from s0
    gstage<0, true, true>(SAH, SAL, WS[0], s0, s1, ma, SBH, SBL, lane, lrow, sc);
    __syncthreads();
    // C: s2 (relu) -> SA, s3 (relu) -> SC, s4 (identity, no store), all from s1
    gstage<1, true, true>(SBH, SBL, WS[1], s1, s2, ma, SAH, SAL, lane, lrow, sc);
    gstage<1, true, true>(SBH, SBL, WS[2], s1, s3, ma, SCH, SCL, lane, lrow, sc);
    gstage<3, false, false>(SBH, SBL, WS[3], s1, dmy, ma, nullptr, nullptr, lane, lrow, sc);
    __syncthreads();
    // D: s5 (tanh) from s2 -> SB; s7 (tanh) from s3 (no store)
    gstage<2, true, true>(SAH, SAL, WS[4], s2, s5, ma, SBH, SBL, lane, lrow, sc);
    gstage<2, false, false>(SCH, SCL, WS[5], s3, dmy, ma, nullptr, nullptr, lane, lrow, sc);
    __syncthreads();
    // E: s6 (sig), s8 (relu), both from s5
    gstage<0, false, false>(SBH, SBL, WS[6], s5, dmy, ma, nullptr, nullptr, lane, lrow, sc);
    gstage<1, false, false>(SBH, SBL, WS[7], s5, dmy, ma, nullptr, nullptr, lane, lrow, sc);

    // h = mean(states 1..8); store hiddens[t]; restage h
#pragma unroll
    for (int j = 0; j < 4; ++j) hp[j] = ma[j] * 0.125f;
#pragma unroll
    for (int j = 0; j < 4; ++j) {
      out[((size_t)t * BB + rb + lrow + j) * 256 + sc] = hp[j];
      if (t == TT - 1)
        out[((size_t)TT * BB + rb + lrow + j) * 256 + sc] = hp[j];
    }
#pragma unroll
    for (int j = 0; j < 4; ++j) put_sv(A0HH, A0HL, lrow + j, sc, hp[j]);
    // loop-top __syncthreads orders A0X/A0H writes for the next W0 stage
  }
}

extern "C" void kernel_launch(void* const* d_in, const int* in_sizes, int n_in,
                              void* d_out, int out_size, void* d_ws, size_t ws_size,
                              hipStream_t stream) {
  (void)in_sizes; (void)n_in; (void)out_size; (void)ws_size;
  const float* X = (const float*)d_in[0];
  const float* Hin = (const float*)d_in[1];
  const float* W0 = (const float*)d_in[2];
  const float* Ws = (const float*)d_in[3];
  char* wq = (char*)d_ws;  // 16 waves * 88 KiB = 1.44 MB
  float* out = (float*)d_out;

  prep<<<5632, 256, 0, stream>>>(W0, Ws, wq);
  darts5<<<16, 1024, 0, stream>>>(X, Hin, wq, out);
}

// Round 6
// 8166.632 us; speedup vs baseline: 3.7453x; 1.2818x over previous
//
#include <hip/hip_runtime.h>

#define TT 256
#define BB 256
#define SW 3100.0f

typedef __attribute__((ext_vector_type(4))) int i32x4;

__device__ __forceinline__ float fsig(float x) { return 1.0f / (1.0f + __expf(-x)); }
__device__ __forceinline__ float ftanh(float x) {
  float e = __expf(-2.0f * fabsf(x));
  float r = (1.0f - e) / (1.0f + e);
  return copysignf(r, x);
}
template <int ACT>
__device__ __forceinline__ float actf(float x) {
  if (ACT == 0) return fsig(x);
  if (ACT == 1) return fmaxf(x, 0.0f);
  if (ACT == 2) return ftanh(x);
  return x;  // identity
}

__device__ __forceinline__ i32x4 mi8(i32x4 a, i32x4 b, i32x4 c) {
  return __builtin_amdgcn_mfma_i32_16x16x64_i8(a, b, c, 0, 0, 0);
}

// [16][256] int8 plane, XOR-swizzled (verified rounds 1-5).
__device__ __forceinline__ int swz(int row, int k) { return row * 256 + (k ^ ((row & 7) << 4)); }

__device__ __forceinline__ i32x4 afrag(const char* P, int lane, int kbase) {
  int row = lane & 15;
  int k0 = kbase + ((lane >> 4) << 4);
  return *(const i32x4*)(P + swz(row, k0));
}

__device__ __forceinline__ int clampc(float v) {
  return (int)rintf(fminf(fmaxf(v, -127.0f), 127.0f));
}
__device__ __forceinline__ int pack4(int a, int b, int c, int d) {
  return (a & 255) | ((b & 255) << 8) | ((c & 255) << 16) | ((d & 255) << 24);
}

// state s = hi/32 + lo/4096
__device__ __forceinline__ void put_sv(char* HI, char* LO, int row, int col, float s) {
  int hi = clampc(s * 32.0f);
  float r = s - (float)hi * (1.0f / 32.0f);
  int lo = clampc(r * 4096.0f);
  int a = swz(row, col);
  HI[a] = (char)hi;
  LO[a] = (char)lo;
}

// lgkmcnt-only barrier: orders LDS, does NOT drain the vmcnt prefetch queue.
__device__ __forceinline__ void barrier_ws() {
  asm volatile("s_waitcnt lgkmcnt(0)" ::: "memory");
  __builtin_amdgcn_s_barrier();
  __builtin_amdgcn_sched_barrier(0);
}

// Prefetch one 16-block (16 KB/wave) stage of weights into registers.
__device__ __forceinline__ void wload(i32x4 (&b)[16], const char* p) {
#pragma unroll
  for (int i = 0; i < 16; ++i) b[i] = *(const i32x4*)(p + i * 1024);
}

// Genotype GEMM MFMA core: A from LDS hi/lo planes, B from register buffer.
__device__ __forceinline__ void gmm(const char* SH, const char* SL, const i32x4 (&wb)[16],
                                    int lane, i32x4 (&ah)[4], i32x4 (&al)[4]) {
#pragma unroll
  for (int n = 0; n < 4; ++n) { ah[n] = (i32x4)(0); al[n] = (i32x4)(0); }
#pragma unroll
  for (int kt = 0; kt < 4; ++kt) {
    i32x4 Ah = afrag(SH, lane, kt * 64);
    i32x4 Al = afrag(SL, lane, kt * 64);
#pragma unroll
    for (int n = 0; n < 4; ++n) {
      ah[n] = mi8(Ah, wb[kt * 4 + n], ah[n]);
      al[n] = mi8(Al, wb[kt * 4 + n], al[n]);
    }
  }
}

template <int ACT, bool KEEP, bool STORE, bool MEAN>
__device__ __forceinline__ void gepi(const i32x4 (&ah)[4], const i32x4 (&al)[4],
                                     const float* spa, const float* spb, float* na, float* nb,
                                     float* ma, float* mb, char* SH, char* SL, int lrow,
                                     int ncol, int scol0) {
  const float INVG = 1.0f / (4096.0f * SW);
#pragma unroll
  for (int j = 0; j < 4; ++j) {
    float cA = ((float)ah[0][j] * 128.0f + (float)al[0][j]) * INVG;
    float hA = ((float)ah[2][j] * 128.0f + (float)al[2][j]) * INVG;
    float sA = spa[j] + fsig(cA) * (actf<ACT>(hA) - spa[j]);
    float cB = ((float)ah[1][j] * 128.0f + (float)al[1][j]) * INVG;
    float hB = ((float)ah[3][j] * 128.0f + (float)al[3][j]) * INVG;
    float sB = spb[j] + fsig(cB) * (actf<ACT>(hB) - spb[j]);
    if (MEAN) { ma[j] += sA; mb[j] += sB; }
    if (KEEP) { na[j] = sA; nb[j] = sB; }
    if (STORE) {
      put_sv(SH, SL, lrow + j, scol0 + ncol, sA);
      put_sv(SH, SL, lrow + j, scol0 + 16 + ncol, sB);
    }
  }
}

// Quantize + permute weights into per-wave lane-ordered int8 block streams.
// wq[wv][blk 0..159][lane][16]: blk 0-15 = W0 x-part (kt*4+nt), 16-31 = W0 h-part,
// 32+s*16+kt*4+nt = genotype stage s in consumption order Ws{0,1,2,3,4,6,5,7}.
__global__ void prep(const float* __restrict__ W0, const float* __restrict__ Ws,
                     char* __restrict__ wq) {
  int gid = blockIdx.x * 256 + threadIdx.x;
  const int mi[8] = {0, 1, 2, 3, 4, 6, 5, 7};
  int wv = gid / 163840;
  int r = gid - wv * 163840;
  int blk = r >> 10, b = r & 1023;
  int l = b >> 4, e = b & 15;
  int kloc = ((l >> 4) << 4) + e;
  int nt, n, k;
  float v;
  if (blk < 32) {
    int part = blk >> 4;  // 0=x rows, 1=h rows of W0
    int q = blk & 15;
    nt = q & 3;
    n = wv * 32 + (nt & 1) * 16 + ((nt >> 1) << 8) + (l & 15);
    k = part * 256 + (q >> 2) * 64 + kloc;
    v = W0[k * 512 + n];
  } else {
    int q = blk - 32;
    int s = q >> 4, w2 = q & 15;
    nt = w2 & 3;
    n = wv * 32 + (nt & 1) * 16 + ((nt >> 1) << 8) + (l & 15);
    k = (w2 >> 2) * 64 + kloc;
    v = Ws[(size_t)mi[s] * 131072 + k * 512 + n];
  }
  wq[gid] = (char)(int)rintf(v * SW);
}

__global__ __launch_bounds__(512, 2) void darts6(const float* __restrict__ X,
                                                 const float* __restrict__ Hin,
                                                 const char* __restrict__ WQ,
                                                 float* __restrict__ out) {
  __shared__ char A0XH[4096], A0XL[4096], A0HH[4096], A0HL[4096];
  __shared__ char SAH[4096], SAL[4096], SBH[4096], SBL[4096], SCH[4096], SCL[4096];

  const int tid = threadIdx.x, lane = tid & 63, wv = tid >> 6;  // 8 waves
  const int ncol = lane & 15, lrow = (lane >> 4) << 2;
  const int scol0 = wv * 32;
  const int rb = blockIdx.x * 16;
  const char* wsrc = WQ + (size_t)wv * 163840 + lane * 16;

  float hpa[4], hpb[4];
#pragma unroll
  for (int j = 0; j < 4; ++j) {
    hpa[j] = Hin[(rb + lrow + j) * 256 + scol0 + ncol];
    hpb[j] = Hin[(rb + lrow + j) * 256 + scol0 + 16 + ncol];
  }
#pragma unroll
  for (int j = 0; j < 4; ++j) {
    put_sv(A0HH, A0HL, lrow + j, scol0 + ncol, hpa[j]);
    put_sv(A0HH, A0HL, lrow + j, scol0 + 16 + ncol, hpb[j]);
  }

  // prologue: x(t=0) into regs; weight stage P0 into bufA
  float4 xr0, xr1;
  {
    int r = tid >> 5, c0 = (tid & 31) * 8;
    const float* xp = X + ((size_t)0 * BB + rb + r) * 256 + c0;
    xr0 = *(const float4*)xp;
    xr1 = *(const float4*)(xp + 4);
  }
  i32x4 bA[16], bB[16];
  wload(bA, wsrc);

  float s0a[4], s0b[4], s1a[4], s1b[4], s2a[4], s2b[4], s3a[4], s3b[4], s5a[4], s5b[4];
  float ma[4], mb[4], dmy[4];

  for (int t = 0; t < TT; ++t) {
    {  // stage x_t regs -> int8 hi/lo LDS planes (x = hi/16 + lo/2048)
      int r = tid >> 5, c0 = (tid & 31) * 8;
      float xs[8] = {xr0.x, xr0.y, xr0.z, xr0.w, xr1.x, xr1.y, xr1.z, xr1.w};
      int hb[8], lb[8];
#pragma unroll
      for (int j = 0; j < 8; ++j) {
        int hi = clampc(xs[j] * 16.0f);
        float res = xs[j] - (float)hi * (1.0f / 16.0f);
        lb[j] = clampc(res * 2048.0f);
        hb[j] = hi;
      }
      int a = swz(r, c0);
      *(int2*)(A0XH + a) = make_int2(pack4(hb[0], hb[1], hb[2], hb[3]),
                                     pack4(hb[4], hb[5], hb[6], hb[7]));
      *(int2*)(A0XL + a) = make_int2(pack4(lb[0], lb[1], lb[2], lb[3]),
                                     pack4(lb[4], lb[5], lb[6], lb[7]));
    }
    barrier_ws();

    // --- P0: W0 x-part (bA); prefetch P1 -> bB ---
    i32x4 axh[4], axl[4];
    wload(bB, wsrc + 16384);
#pragma unroll
    for (int n = 0; n < 4; ++n) { axh[n] = (i32x4)(0); axl[n] = (i32x4)(0); }
#pragma unroll
    for (int kt = 0; kt < 4; ++kt) {
      i32x4 Axh = afrag(A0XH, lane, kt * 64);
      i32x4 Axl = afrag(A0XL, lane, kt * 64);
#pragma unroll
      for (int n = 0; n < 4; ++n) {
        axh[n] = mi8(Axh, bA[kt * 4 + n], axh[n]);
        axl[n] = mi8(Axl, bA[kt * 4 + n], axl[n]);
      }
    }
    // x-hi unit (1/16) = 2x state-hi unit (1/32); x-lo (1/2048) = 2x state-lo: double accs
#pragma unroll
    for (int n = 0; n < 4; ++n) { axh[n] = axh[n] + axh[n]; axl[n] = axl[n] + axl[n]; }

    // --- P1: W0 h-part (bB) accumulates into scaled accs; prefetch P2 -> bA ---
    wload(bA, wsrc + 2 * 16384);
#pragma unroll
    for (int kt = 0; kt < 4; ++kt) {
      i32x4 Ahh = afrag(A0HH, lane, kt * 64);
      i32x4 Ahl = afrag(A0HL, lane, kt * 64);
#pragma unroll
      for (int n = 0; n < 4; ++n) {
        axh[n] = mi8(Ahh, bB[kt * 4 + n], axh[n]);
        axl[n] = mi8(Ahl, bB[kt * 4 + n], axl[n]);
      }
    }
    gepi<2, true, true, false>(axh, axl, hpa, hpb, s0a, s0b, ma, mb, SAH, SAL, lrow, ncol, scol0);
    barrier_ws();

#pragma unroll
    for (int j = 0; j < 4; ++j) { ma[j] = 0.f; mb[j] = 0.f; }

    i32x4 gh[4], gl[4];
    // --- P2: s1 = sigmoid step (Ws0) from SA(s0) -> SB; prefetch P3 -> bB ---
    wload(bB, wsrc + 3 * 16384);
    gmm(SAH, SAL, bA, lane, gh, gl);
    gepi<0, true, true, true>(gh, gl, s0a, s0b, s1a, s1b, ma, mb, SBH, SBL, lrow, ncol, scol0);
    barrier_ws();

    // --- P3: s2 relu -> SA (bB); prefetch P4 -> bA ---
    wload(bA, wsrc + 4 * 16384);
    gmm(SBH, SBL, bB, lane, gh, gl);
    gepi<1, true, true, true>(gh, gl, s1a, s1b, s2a, s2b, ma, mb, SAH, SAL, lrow, ncol, scol0);
    // --- P4: s3 relu -> SC (bA); prefetch P5 -> bB ---
    wload(bB, wsrc + 5 * 16384);
    gmm(SBH, SBL, bA, lane, gh, gl);
    gepi<1, true, true, true>(gh, gl, s1a, s1b, s3a, s3b, ma, mb, SCH, SCL, lrow, ncol, scol0);
    // --- P5: s4 identity, no store (bB); prefetch P6 -> bA ---
    wload(bA, wsrc + 6 * 16384);
    gmm(SBH, SBL, bB, lane, gh, gl);
    gepi<3, false, false, true>(gh, gl, s1a, s1b, dmy, dmy, ma, mb, nullptr, nullptr, lrow, ncol, scol0);
    barrier_ws();

    // --- P6: s5 tanh (Ws4) from SA(s2) -> SB (bA); prefetch P7 -> bB ---
    wload(bB, wsrc + 7 * 16384);
    gmm(SAH, SAL, bA, lane, gh, gl);
    gepi<2, true, true, true>(gh, gl, s2a, s2b, s5a, s5b, ma, mb, SBH, SBL, lrow, ncol, scol0);
    // --- P7: s7 tanh (Ws6) from SC(s3), no store (bB); prefetch P8 -> bA ---
    wload(bA, wsrc + 8 * 16384);
    gmm(SCH, SCL, bB, lane, gh, gl);
    gepi<2, false, false, true>(gh, gl, s3a, s3b, dmy, dmy, ma, mb, nullptr, nullptr, lrow, ncol, scol0);
    // prefetch x(t+1) into regs (HBM latency hides under stage E)
    if (t + 1 < TT) {
      int r = tid >> 5, c0 = (tid & 31) * 8;
      const float* xp = X + ((size_t)(t + 1) * BB + rb + r) * 256 + c0;
      xr0 = *(const float4*)xp;
      xr1 = *(const float4*)(xp + 4);
    }
    barrier_ws();

    // --- P8: s6 sig (Ws5) from SB(s5) (bA); prefetch P9 -> bB ---
    wload(bB, wsrc + 9 * 16384);
    gmm(SBH, SBL, bA, lane, gh, gl);
    gepi<0, false, false, true>(gh, gl, s5a, s5b, dmy, dmy, ma, mb, nullptr, nullptr, lrow, ncol, scol0);
    // --- P9: s8 relu (Ws7) from SB(s5) (bB); prefetch P0 of t+1 -> bA ---
    wload(bA, wsrc);
    gmm(SBH, SBL, bB, lane, gh, gl);
    gepi<1, false, false, true>(gh, gl, s5a, s5b, dmy, dmy, ma, mb, nullptr, nullptr, lrow, ncol, scol0);

    // h = mean(states 1..8); store hiddens[t]; restage h
#pragma unroll
    for (int j = 0; j < 4; ++j) { hpa[j] = ma[j] * 0.125f; hpb[j] = mb[j] * 0.125f; }
#pragma unroll
    for (int j = 0; j < 4; ++j) {
      size_t base = ((size_t)t * BB + rb + lrow + j) * 256;
      out[base + scol0 + ncol] = hpa[j];
      out[base + scol0 + 16 + ncol] = hpb[j];
    }
    if (t == TT - 1) {
#pragma unroll
      for (int j = 0; j < 4; ++j) {
        size_t base = ((size_t)TT * BB + rb + lrow + j) * 256;
        out[base + scol0 + ncol] = hpa[j];
        out[base + scol0 + 16 + ncol] = hpb[j];
      }
    }
#pragma unroll
    for (int j = 0; j < 4; ++j) {
      put_sv(A0HH, A0HL, lrow + j, scol0 + ncol, hpa[j]);
      put_sv(A0HH, A0HL, lrow + j, scol0 + 16 + ncol, hpb[j]);
    }
    // loop-top barrier orders A0X/A0H LDS writes for the next W0 stage
  }
}

extern "C" void kernel_launch(void* const* d_in, const int* in_sizes, int n_in,
                              void* d_out, int out_size, void* d_ws, size_t ws_size,
                              hipStream_t stream) {
  (void)in_sizes; (void)n_in; (void)out_size; (void)ws_size;
  const float* X = (const float*)d_in[0];
  const float* Hin = (const float*)d_in[1];
  const float* W0 = (const float*)d_in[2];
  const float* Ws = (const float*)d_in[3];
  char* wq = (char*)d_ws;  // 8 waves * 160 KiB = 1.28 MB
  float* out = (float*)d_out;

  prep<<<5120, 256, 0, stream>>>(W0, Ws, wq);
  darts6<<<16, 512, 0, stream>>>(X, Hin, wq, out);
}